// Round 5
// baseline (116.797 us; speedup 1.0000x reference)
//
#include <hip/hip_runtime.h>
#include <math.h>

#define BB 8
#define TT 4096
#define EE 64
#define DD 8
// (1/sqrt(8)) * log2(e): folded into q so p = exp2(score) directly
#define QSCALE 0.51012604f
// fixed softmax shift, implemented as MFMA C-init; cancels in normalization
#define CSHIFT -12.0f

typedef _Float16 half8  __attribute__((ext_vector_type(8)));
typedef _Float16 half4v __attribute__((ext_vector_type(4)));
typedef float    floatx4 __attribute__((ext_vector_type(4)));

// ---------------------------------------------------------------------------
// Kernel 1: projections (unchanged from round 4). Block owns 32 rows
// t = g*512 + tbase + j so the ks "reshape" scatter is one contiguous
// 512-B region. vT rows: 0-7 = v^T, row 8 = ones (denominator trick).
// ---------------------------------------------------------------------------
__global__ __launch_bounds__(256) void proj_kernel(
    const float* __restrict__ x,
    const float* __restrict__ Wq, const float* __restrict__ bq,
    const float* __restrict__ Wk, const float* __restrict__ bk,
    const float* __restrict__ Wv, const float* __restrict__ bv,
    _Float16* __restrict__ qh, _Float16* __restrict__ ks, _Float16* __restrict__ vT)
{
    __shared__ float    xs[32][EE + 1];
    __shared__ _Float16 qsm[256];   // [g][j][d] == tid order
    __shared__ _Float16 ksm[256];   // [j][d][g]
    __shared__ _Float16 vsm[256];   // [d][r]

    const int tid   = threadIdx.x;
    const int blk   = blockIdx.x;
    const int b     = blk >> 7;
    const int tbase = (blk & 127) << 2;

#pragma unroll
    for (int m2 = 0; m2 < 2; ++m2) {
        int r = (tid >> 4) + (m2 << 4);
        int c = (tid & 15) << 2;
        int t = ((r >> 2) << 9) + tbase + (r & 3);
        float4 a = *(const float4*)(x + (size_t)(b * TT + t) * EE + c);
        xs[r][c+0] = a.x; xs[r][c+1] = a.y; xs[r][c+2] = a.z; xs[r][c+3] = a.w;
    }
    __syncthreads();

    const int r = tid >> 3;
    const int d = tid & 7;
    float accq = bq[d], acck = bk[d], accv = bv[d];
#pragma unroll
    for (int e = 0; e < EE; ++e) {
        float xv = xs[r][e];
        accq = fmaf(xv, Wq[e*DD + d], accq);
        acck = fmaf(xv, Wk[e*DD + d], acck);
        accv = fmaf(xv, Wv[e*DD + d], accv);
    }
    qsm[tid] = (_Float16)(accq * QSCALE);
    ksm[((r & 3) << 6) + (d << 3) + (r >> 2)] = (_Float16)acck;
    vsm[(d << 5) + r] = (_Float16)accv;
    __syncthreads();

    if (tid < 32) {
        half8 qv = *(half8*)(qsm + tid * 8);
        *(half8*)(qh + (size_t)b*(TT*DD) + (size_t)(tid >> 2)*(512*DD)
                     + (size_t)tbase*DD + ((tid & 3) << 3)) = qv;
        half8 kv = *(half8*)(ksm + tid * 8);
        *(half8*)(ks + (size_t)b*(TT*DD) + (size_t)tbase*64 + tid * 8) = kv;
    } else if (tid >= 64 && tid < 128) {
        int idx = tid - 64, d2 = idx >> 3, g2 = idx & 7;
        half4v vv = *(half4v*)(vsm + (d2 << 5) + (g2 << 2));
        *(half4v*)(vT + (size_t)b*(16*TT) + (size_t)d2*TT + (g2 << 9) + tbase) = vv;
    } else if (tid >= 128 && tid < 136) {
        int g2 = tid - 128;
        half4v ones = {(_Float16)1.0f, (_Float16)1.0f, (_Float16)1.0f, (_Float16)1.0f};
        *(half4v*)(vT + (size_t)b*(16*TT) + (size_t)8*TT + (g2 << 9) + tbase) = ones;
    }
}

// ---------------------------------------------------------------------------
// Kernel 2: MFMA flash attention, fixed-shift softmax. Round-5 changes:
//  - A-tile and B-tile item loops SPLIT (no per-item isA/qf/acc selects)
//  - exact-zero-score check dropped (measure-zero event, error << 5e-2)
//  - ks fragments software-pipelined (prefetch next item's 4 x b128)
//  - __launch_bounds__(512,8): force VGPR<=64 so 8 waves/SIMD stay resident
// Per-wave items: ceil variants of ntA/8 + ntB/8 — max exactly 9, uniform.
// ---------------------------------------------------------------------------
__global__ __launch_bounds__(512, 8) void attn_kernel(
    const _Float16* __restrict__ qh, const _Float16* __restrict__ ks,
    const _Float16* __restrict__ vT, float* __restrict__ out)
{
    __shared__ floatx4 obuf[2][8][64];

    const int lane = threadIdx.x & 63;
    const int wave = threadIdx.x >> 6;
    const int g = lane >> 4;
    const int n = lane & 15;

    const int blk = blockIdx.x;
    const int bb  = blk >> 7;
    const int p   = blk & 127;
    const int ntA = (p >> 2) + 1;
    const int ntB = ((255 - p) >> 2) + 1;
    const int r0A = p << 4;
    const int r0B = (255 - p) << 4;

    const _Float16* ksb = ks + (size_t)bb * (TT*DD);
    const _Float16* vTb = vT + (size_t)bb * (16*TT);
    const _Float16* vrow = vTb + (size_t)n * TT + (g << 3);

    half8 qfA, qfB;
    {
        half8 z;
#pragma unroll
        for (int j = 0; j < 8; ++j) z[j] = (_Float16)0.0f;
        qfA = z; qfB = z;
        if (g == 0) {
            qfA = *(const half8*)(qh + ((size_t)bb*TT + r0A + n) * DD);
            qfB = *(const half8*)(qh + ((size_t)bb*TT + r0B + n) * DD);
        }
    }

    floatx4 oA = {0.f, 0.f, 0.f, 0.f};
    floatx4 oB = {0.f, 0.f, 0.f, 0.f};
    const floatx4 C12 = {CSHIFT, CSHIFT, CSHIFT, CSHIFT};

    const int  srcA  = ((g & 1) << 5) | n;   // P^T shuffle-transpose sources
    const int  srcB  = srcA + 16;
    const bool hiSub = (g & 2) != 0;

#define ATTN_LOOP(NT, R0, QF, OACC)                                             \
    {                                                                           \
        int i = wave;                                                           \
        half8 ck0, ck1, ck2, ck3;                                               \
        if (i < (NT)) {                                                         \
            const _Float16* kp = ksb + (size_t)(i << 6) * DD + (size_t)n * DD;  \
            ck0 = *(const half8*)(kp);                                          \
            ck1 = *(const half8*)(kp + 16 * DD);                                \
            ck2 = *(const half8*)(kp + 32 * DD);                                \
            ck3 = *(const half8*)(kp + 48 * DD);                                \
        }                                                                       \
        for (; i < (NT); i += 8) {                                              \
            const int t2base = i << 6;                                          \
            int inx = i + 8; if (inx >= (NT)) inx = i;                          \
            const _Float16* kpn = ksb + (size_t)(inx << 6) * DD + (size_t)n * DD;\
            half8 nk0 = *(const half8*)(kpn);                                   \
            half8 nk1 = *(const half8*)(kpn + 16 * DD);                         \
            half8 nk2 = *(const half8*)(kpn + 32 * DD);                         \
            half8 nk3 = *(const half8*)(kpn + 48 * DD);                         \
            half8 va0 = *(const half8*)(vrow + t2base);                         \
            half8 va1 = *(const half8*)(vrow + t2base + 32);                    \
            floatx4 S[4];                                                       \
            S[0] = __builtin_amdgcn_mfma_f32_16x16x32_f16(ck0, QF, C12, 0, 0, 0);\
            S[1] = __builtin_amdgcn_mfma_f32_16x16x32_f16(ck1, QF, C12, 0, 0, 0);\
            S[2] = __builtin_amdgcn_mfma_f32_16x16x32_f16(ck2, QF, C12, 0, 0, 0);\
            S[3] = __builtin_amdgcn_mfma_f32_16x16x32_f16(ck3, QF, C12, 0, 0, 0);\
            if (t2base + 63 > (R0)) {                                           \
                const int lim = (R0) + n - t2base - (g << 2);                   \
                _Pragma("unroll")                                               \
                for (int s = 0; s < 4; ++s)                                     \
                    _Pragma("unroll")                                           \
                    for (int rr = 0; rr < 4; ++rr)                              \
                        if ((s << 4) + rr > lim) S[s][rr] = -INFINITY;          \
            }                                                                   \
            int lo[4], hi[4];                                                   \
            _Pragma("unroll")                                                   \
            for (int s = 0; s < 4; ++s) {                                       \
                float p0 = __builtin_amdgcn_exp2f(S[s][0]);                     \
                float p1 = __builtin_amdgcn_exp2f(S[s][1]);                     \
                float p2 = __builtin_amdgcn_exp2f(S[s][2]);                     \
                float p3 = __builtin_amdgcn_exp2f(S[s][3]);                     \
                lo[s] = __builtin_bit_cast(int, __builtin_amdgcn_cvt_pkrtz(p0, p1));\
                hi[s] = __builtin_bit_cast(int, __builtin_amdgcn_cvt_pkrtz(p2, p3));\
            }                                                                   \
            _Pragma("unroll")                                                   \
            for (int pv = 0; pv < 2; ++pv) {                                    \
                const int sA2 = pv << 1, sB2 = sA2 | 1;                         \
                int a0 = __shfl(lo[sA2], srcA, 64), b0 = __shfl(lo[sB2], srcA, 64);\
                int a1 = __shfl(hi[sA2], srcA, 64), b1 = __shfl(hi[sB2], srcA, 64);\
                int a2 = __shfl(lo[sA2], srcB, 64), b2 = __shfl(lo[sB2], srcB, 64);\
                int a3 = __shfl(hi[sA2], srcB, 64), b3 = __shfl(hi[sB2], srcB, 64);\
                int4 wi;                                                        \
                wi.x = hiSub ? b0 : a0;                                         \
                wi.y = hiSub ? b1 : a1;                                         \
                wi.z = hiSub ? b2 : a2;                                         \
                wi.w = hiSub ? b3 : a3;                                         \
                half8 pb = __builtin_bit_cast(half8, wi);                       \
                half8 vv = pv ? va1 : va0;                                      \
                OACC = __builtin_amdgcn_mfma_f32_16x16x32_f16(vv, pb, OACC, 0, 0, 0);\
            }                                                                   \
            ck0 = nk0; ck1 = nk1; ck2 = nk2; ck3 = nk3;                         \
        }                                                                       \
    }

    ATTN_LOOP(ntA, r0A, qfA, oA)
    ATTN_LOOP(ntB, r0B, qfB, oB)
#undef ATTN_LOOP

    obuf[0][wave][lane] = oA;
    obuf[1][wave][lane] = oB;
    __syncthreads();

    // ---- merge: plain sum of 8 partials (fixed shift -> no rebasing) ----
    if (wave < 2) {
        floatx4 osum = {0.f, 0.f, 0.f, 0.f};
#pragma unroll
        for (int w = 0; w < 8; ++w) osum += obuf[wave][w][lane];
        const float l    = __shfl(osum[0], 32 + n, 64);  // O^T[8][t1]
        const float linv = 1.0f / l;
        const int   r0   = wave ? r0B : r0A;
        if (g < 2) {
            float4 res;
            res.x = osum[0] * linv; res.y = osum[1] * linv;
            res.z = osum[2] * linv; res.w = osum[3] * linv;
            *(float4*)(out + (((size_t)bb * TT + r0 + n) * DD) + (g << 2)) = res;
        }
    }
}

extern "C" void kernel_launch(void* const* d_in, const int* in_sizes, int n_in,
                              void* d_out, int out_size, void* d_ws, size_t ws_size,
                              hipStream_t stream) {
    const float* x  = (const float*)d_in[0];
    const float* Wq = (const float*)d_in[1];
    const float* bq = (const float*)d_in[2];
    const float* Wk = (const float*)d_in[3];
    const float* bk = (const float*)d_in[4];
    const float* Wv = (const float*)d_in[5];
    const float* bv = (const float*)d_in[6];
    float* out = (float*)d_out;

    _Float16* qhp = (_Float16*)d_ws;                       // B*T*D
    _Float16* ksp = qhp + (size_t)BB * TT * DD;            // B*T*D
    _Float16* vTp = ksp + (size_t)BB * TT * DD;            // B*16*T

    proj_kernel<<<BB * TT / 32, 256, 0, stream>>>(x, Wq, bq, Wk, bk, Wv, bv, qhp, ksp, vTp);
    attn_kernel<<<1024, 512, 0, stream>>>(qhp, ksp, vTp, out);
}

// Round 6
// 100.737 us; speedup vs baseline: 1.1594x; 1.1594x over previous
//
#include <hip/hip_runtime.h>
#include <math.h>

#define BB 8
#define TT 4096
#define EE 64
#define DD 8
// (1/sqrt(8)) * log2(e): folded into q so p = exp2(score) directly
#define QSCALE 0.51012604f
// fixed softmax shift, implemented as MFMA C-init; cancels in normalization
#define CSHIFT -12.0f

typedef _Float16 half8  __attribute__((ext_vector_type(8)));
typedef _Float16 half4v __attribute__((ext_vector_type(4)));
typedef float    floatx4 __attribute__((ext_vector_type(4)));

// ---------------------------------------------------------------------------
// Kernel 1: projections (unchanged from round 4). Block owns 32 rows
// t = g*512 + tbase + j so the ks "reshape" scatter is one contiguous
// 512-B region. vT rows: 0-7 = v^T, row 8 = ones (denominator trick).
// ---------------------------------------------------------------------------
__global__ __launch_bounds__(256) void proj_kernel(
    const float* __restrict__ x,
    const float* __restrict__ Wq, const float* __restrict__ bq,
    const float* __restrict__ Wk, const float* __restrict__ bk,
    const float* __restrict__ Wv, const float* __restrict__ bv,
    _Float16* __restrict__ qh, _Float16* __restrict__ ks, _Float16* __restrict__ vT)
{
    __shared__ float    xs[32][EE + 1];
    __shared__ _Float16 qsm[256];   // [g][j][d] == tid order
    __shared__ _Float16 ksm[256];   // [j][d][g]
    __shared__ _Float16 vsm[256];   // [d][r]

    const int tid   = threadIdx.x;
    const int blk   = blockIdx.x;
    const int b     = blk >> 7;
    const int tbase = (blk & 127) << 2;

#pragma unroll
    for (int m2 = 0; m2 < 2; ++m2) {
        int r = (tid >> 4) + (m2 << 4);
        int c = (tid & 15) << 2;
        int t = ((r >> 2) << 9) + tbase + (r & 3);
        float4 a = *(const float4*)(x + (size_t)(b * TT + t) * EE + c);
        xs[r][c+0] = a.x; xs[r][c+1] = a.y; xs[r][c+2] = a.z; xs[r][c+3] = a.w;
    }
    __syncthreads();

    const int r = tid >> 3;
    const int d = tid & 7;
    float accq = bq[d], acck = bk[d], accv = bv[d];
#pragma unroll
    for (int e = 0; e < EE; ++e) {
        float xv = xs[r][e];
        accq = fmaf(xv, Wq[e*DD + d], accq);
        acck = fmaf(xv, Wk[e*DD + d], acck);
        accv = fmaf(xv, Wv[e*DD + d], accv);
    }
    qsm[tid] = (_Float16)(accq * QSCALE);
    ksm[((r & 3) << 6) + (d << 3) + (r >> 2)] = (_Float16)acck;
    vsm[(d << 5) + r] = (_Float16)accv;
    __syncthreads();

    if (tid < 32) {
        half8 qv = *(half8*)(qsm + tid * 8);
        *(half8*)(qh + (size_t)b*(TT*DD) + (size_t)(tid >> 2)*(512*DD)
                     + (size_t)tbase*DD + ((tid & 3) << 3)) = qv;
        half8 kv = *(half8*)(ksm + tid * 8);
        *(half8*)(ks + (size_t)b*(TT*DD) + (size_t)tbase*64 + tid * 8) = kv;
    } else if (tid >= 64 && tid < 128) {
        int idx = tid - 64, d2 = idx >> 3, g2 = idx & 7;
        half4v vv = *(half4v*)(vsm + (d2 << 5) + (g2 << 2));
        *(half4v*)(vT + (size_t)b*(16*TT) + (size_t)d2*TT + (g2 << 9) + tbase) = vv;
    } else if (tid >= 128 && tid < 136) {
        int g2 = tid - 128;
        half4v ones = {(_Float16)1.0f, (_Float16)1.0f, (_Float16)1.0f, (_Float16)1.0f};
        *(half4v*)(vT + (size_t)b*(16*TT) + (size_t)8*TT + (g2 << 9) + tbase) = ones;
    }
}

// ---------------------------------------------------------------------------
// Kernel 2: MFMA flash attention, fixed-shift softmax. Round-6:
//  - split A/B item loops, no exact-zero check (kept from round 5)
//  - NO explicit K-prefetch (round-5 spill source removed)
//  - __launch_bounds__(512,4): 128-VGPR cap, compiler lands ~<=64 naturally
// Per-wave items: max exactly 9, uniform across all blocks (ntA+ntB = 65).
// ---------------------------------------------------------------------------
__global__ __launch_bounds__(512, 4) void attn_kernel(
    const _Float16* __restrict__ qh, const _Float16* __restrict__ ks,
    const _Float16* __restrict__ vT, float* __restrict__ out)
{
    __shared__ floatx4 obuf[2][8][64];

    const int lane = threadIdx.x & 63;
    const int wave = threadIdx.x >> 6;
    const int g = lane >> 4;
    const int n = lane & 15;

    const int blk = blockIdx.x;
    const int bb  = blk >> 7;
    const int p   = blk & 127;
    const int ntA = (p >> 2) + 1;
    const int ntB = ((255 - p) >> 2) + 1;
    const int r0A = p << 4;
    const int r0B = (255 - p) << 4;

    const _Float16* ksb = ks + (size_t)bb * (TT*DD);
    const _Float16* vTb = vT + (size_t)bb * (16*TT);
    const _Float16* vrow = vTb + (size_t)n * TT + (g << 3);

    half8 qfA, qfB;
    {
        half8 z;
#pragma unroll
        for (int j = 0; j < 8; ++j) z[j] = (_Float16)0.0f;
        qfA = z; qfB = z;
        if (g == 0) {
            qfA = *(const half8*)(qh + ((size_t)bb*TT + r0A + n) * DD);
            qfB = *(const half8*)(qh + ((size_t)bb*TT + r0B + n) * DD);
        }
    }

    floatx4 oA = {0.f, 0.f, 0.f, 0.f};
    floatx4 oB = {0.f, 0.f, 0.f, 0.f};
    const floatx4 C12 = {CSHIFT, CSHIFT, CSHIFT, CSHIFT};

    const int  srcA  = ((g & 1) << 5) | n;   // P^T shuffle-transpose sources
    const int  srcB  = srcA + 16;
    const bool hiSub = (g & 2) != 0;

#define ATTN_LOOP(NT, R0, QF, OACC)                                             \
    for (int i = wave; i < (NT); i += 8) {                                      \
        const int t2base = i << 6;                                              \
        const _Float16* kp = ksb + (size_t)(t2base + n) * DD;                   \
        half8 ck0 = *(const half8*)(kp);                                        \
        half8 ck1 = *(const half8*)(kp + 16 * DD);                              \
        half8 ck2 = *(const half8*)(kp + 32 * DD);                              \
        half8 ck3 = *(const half8*)(kp + 48 * DD);                              \
        half8 va0 = *(const half8*)(vrow + t2base);                             \
        half8 va1 = *(const half8*)(vrow + t2base + 32);                        \
        floatx4 S[4];                                                           \
        S[0] = __builtin_amdgcn_mfma_f32_16x16x32_f16(ck0, QF, C12, 0, 0, 0);   \
        S[1] = __builtin_amdgcn_mfma_f32_16x16x32_f16(ck1, QF, C12, 0, 0, 0);   \
        S[2] = __builtin_amdgcn_mfma_f32_16x16x32_f16(ck2, QF, C12, 0, 0, 0);   \
        S[3] = __builtin_amdgcn_mfma_f32_16x16x32_f16(ck3, QF, C12, 0, 0, 0);   \
        if (t2base + 63 > (R0)) {                                               \
            const int lim = (R0) + n - t2base - (g << 2);                       \
            _Pragma("unroll")                                                   \
            for (int s = 0; s < 4; ++s)                                         \
                _Pragma("unroll")                                               \
                for (int rr = 0; rr < 4; ++rr)                                  \
                    if ((s << 4) + rr > lim) S[s][rr] = -INFINITY;              \
        }                                                                       \
        int lo[4], hi[4];                                                       \
        _Pragma("unroll")                                                       \
        for (int s = 0; s < 4; ++s) {                                           \
            float p0 = __builtin_amdgcn_exp2f(S[s][0]);                         \
            float p1 = __builtin_amdgcn_exp2f(S[s][1]);                         \
            float p2 = __builtin_amdgcn_exp2f(S[s][2]);                         \
            float p3 = __builtin_amdgcn_exp2f(S[s][3]);                         \
            lo[s] = __builtin_bit_cast(int, __builtin_amdgcn_cvt_pkrtz(p0, p1));\
            hi[s] = __builtin_bit_cast(int, __builtin_amdgcn_cvt_pkrtz(p2, p3));\
        }                                                                       \
        _Pragma("unroll")                                                       \
        for (int pv = 0; pv < 2; ++pv) {                                        \
            const int sA2 = pv << 1, sB2 = sA2 | 1;                             \
            int a0 = __shfl(lo[sA2], srcA, 64), b0 = __shfl(lo[sB2], srcA, 64); \
            int a1 = __shfl(hi[sA2], srcA, 64), b1 = __shfl(hi[sB2], srcA, 64); \
            int a2 = __shfl(lo[sA2], srcB, 64), b2 = __shfl(lo[sB2], srcB, 64); \
            int a3 = __shfl(hi[sA2], srcB, 64), b3 = __shfl(hi[sB2], srcB, 64); \
            int4 wi;                                                            \
            wi.x = hiSub ? b0 : a0;                                             \
            wi.y = hiSub ? b1 : a1;                                             \
            wi.z = hiSub ? b2 : a2;                                             \
            wi.w = hiSub ? b3 : a3;                                             \
            half8 pb = __builtin_bit_cast(half8, wi);                           \
            half8 vv = pv ? va1 : va0;                                          \
            OACC = __builtin_amdgcn_mfma_f32_16x16x32_f16(vv, pb, OACC, 0, 0, 0);\
        }                                                                       \
    }

    ATTN_LOOP(ntA, r0A, qfA, oA)
    ATTN_LOOP(ntB, r0B, qfB, oB)
#undef ATTN_LOOP

    obuf[0][wave][lane] = oA;
    obuf[1][wave][lane] = oB;
    __syncthreads();

    // ---- merge: plain sum of 8 partials (fixed shift -> no rebasing) ----
    if (wave < 2) {
        floatx4 osum = {0.f, 0.f, 0.f, 0.f};
#pragma unroll
        for (int w = 0; w < 8; ++w) osum += obuf[wave][w][lane];
        const float l    = __shfl(osum[0], 32 + n, 64);  // O^T[8][t1]
        const float linv = 1.0f / l;
        const int   r0   = wave ? r0B : r0A;
        if (g < 2) {
            float4 res;
            res.x = osum[0] * linv; res.y = osum[1] * linv;
            res.z = osum[2] * linv; res.w = osum[3] * linv;
            *(float4*)(out + (((size_t)bb * TT + r0 + n) * DD) + (g << 2)) = res;
        }
    }
}

extern "C" void kernel_launch(void* const* d_in, const int* in_sizes, int n_in,
                              void* d_out, int out_size, void* d_ws, size_t ws_size,
                              hipStream_t stream) {
    const float* x  = (const float*)d_in[0];
    const float* Wq = (const float*)d_in[1];
    const float* bq = (const float*)d_in[2];
    const float* Wk = (const float*)d_in[3];
    const float* bk = (const float*)d_in[4];
    const float* Wv = (const float*)d_in[5];
    const float* bv = (const float*)d_in[6];
    float* out = (float*)d_out;

    _Float16* qhp = (_Float16*)d_ws;                       // B*T*D
    _Float16* ksp = qhp + (size_t)BB * TT * DD;            // B*T*D
    _Float16* vTp = ksp + (size_t)BB * TT * DD;            // B*16*T

    proj_kernel<<<BB * TT / 32, 256, 0, stream>>>(x, Wq, bq, Wk, bk, Wv, bv, qhp, ksp, vTp);
    attn_kernel<<<1024, 512, 0, stream>>>(qhp, ksp, vTp, out);
}